// Round 1
// baseline (160.897 us; speedup 1.0000x reference)
//
#include <hip/hip_runtime.h>

#define NS 65536
#define DD 32
#define RR 128
#define SPB 16            // samples per block
#define STR 132           // padded LDS row stride (floats)
#define NQ (SPB * 4)      // 8-float "quarters" in the block's X tile

// R5: break the scalar-memory latency chain.
// R4 loaded X rows via uniform SGPR (SMEM) loads. SMEM returns are unordered ->
// compiler emits lgkmcnt(0) at every use, collapsing the 1-sample prefetch to
// depth ~0: each of the 16 samples serially pays ~900cy of miss latency
// (VALUBusy 33%, 45.5us). R5 uses per-lane VECTOR loads (identical address
// across lanes -> one 128B line per request, L1 broadcast). vmcnt is in-order,
// so a 4-slot ring of 8-float quarters keeps ~3 loads in flight and partial
// vmcnt waits hide L1/L2 latency under the FMA work.
// To stay at <=128 VGPR (4 waves/SIMD, matching the 18KB-LDS 8-block/CU cap),
// the rule work is split into two X sweeps:
//   A: membership (w/naw: 64 regs) -> st -> SBUF
//   B: consequent (ck/bias: 34 regs) -> pv = st*ro -> PBUF (X re-read hits L1)
// sched_barrier(0) keeps phase-B param loads from hoisting into phase A.
// Accumulation order matches R4 exactly -> bit-identical outputs.
__global__ __launch_bounds__(128, 4) void anfis_main(
    const float* __restrict__ X, const float* __restrict__ A,
    const float* __restrict__ B, const float* __restrict__ C,
    float* __restrict__ out_pred, float* __restrict__ out_str,
    float* __restrict__ out_norm)
{
    __shared__ float SBUF[SPB * STR];   // strengths, row = sample-in-block
    __shared__ float PBUF[SPB * STR];   // strength * rule_out
    __shared__ float pS[SPB][8];
    __shared__ float pD[SPB][8];
    __shared__ float scale_lds[SPB];

    const int tid   = threadIdx.x;      // rule id
    const int nbase = blockIdx.x * SPB;

    // Laundered zero in a VGPR: makes the X address non-uniform-provable so the
    // compiler emits global_load (VMEM/vmcnt, in-order) instead of s_load.
    int vzero = 0;
    asm("" : "+v"(vzero));
    const float* xp = X + (size_t)nbase * DD + vzero;

    // ---------------- phase A: membership -> st -> SBUF ----------------
    {
        float w_[DD], naw_[DD];
        {
            const float4* av = (const float4*)(A + tid * DD);
            const float4* bv = (const float4*)(B + tid * DD);
            #pragma unroll
            for (int i = 0; i < 8; ++i) {
                float4 va = av[i], vb = bv[i];
                float w0 = 0.8493218003f * __builtin_amdgcn_rcpf(fmaxf(vb.x, 1e-8f));
                float w1 = 0.8493218003f * __builtin_amdgcn_rcpf(fmaxf(vb.y, 1e-8f));
                float w2 = 0.8493218003f * __builtin_amdgcn_rcpf(fmaxf(vb.z, 1e-8f));
                float w3 = 0.8493218003f * __builtin_amdgcn_rcpf(fmaxf(vb.w, 1e-8f));
                w_[4*i+0] = w0; naw_[4*i+0] = -va.x * w0;
                w_[4*i+1] = w1; naw_[4*i+1] = -va.y * w1;
                w_[4*i+2] = w2; naw_[4*i+2] = -va.z * w2;
                w_[4*i+3] = w3; naw_[4*i+3] = -va.w * w3;
            }
        }
        #pragma unroll
        for (int d = 0; d < DD; ++d) asm("" : "+v"(w_[d]), "+v"(naw_[d]));

        float4 q[4][2];                 // ring: 8 floats per slot, depth-3 prefetch
        #pragma unroll
        for (int k = 0; k < 3; ++k) {
            const float4* p = (const float4*)(xp + k * 8);
            q[k][0] = p[0]; q[k][1] = p[1];
        }
        float s0 = 0.f, s1 = 0.f, s2 = 0.f, s3 = 0.f;
        #pragma unroll
        for (int k = 0; k < NQ; ++k) {
            if (k + 3 < NQ) {
                const float4* p = (const float4*)(xp + (k + 3) * 8);
                q[(k + 3) & 3][0] = p[0]; q[(k + 3) & 3][1] = p[1];
            }
            const int d0 = (k & 3) * 8;
            float4 v0 = q[k & 3][0], v1 = q[k & 3][1];
            float t0 = fmaf(v0.x, w_[d0+0], naw_[d0+0]); s0 = fmaf(t0, t0, s0);
            float t1 = fmaf(v0.y, w_[d0+1], naw_[d0+1]); s1 = fmaf(t1, t1, s1);
            float t2 = fmaf(v0.z, w_[d0+2], naw_[d0+2]); s2 = fmaf(t2, t2, s2);
            float t3 = fmaf(v0.w, w_[d0+3], naw_[d0+3]); s3 = fmaf(t3, t3, s3);
            float t4 = fmaf(v1.x, w_[d0+4], naw_[d0+4]); s0 = fmaf(t4, t4, s0);
            float t5 = fmaf(v1.y, w_[d0+5], naw_[d0+5]); s1 = fmaf(t5, t5, s1);
            float t6 = fmaf(v1.z, w_[d0+6], naw_[d0+6]); s2 = fmaf(t6, t6, s2);
            float t7 = fmaf(v1.w, w_[d0+7], naw_[d0+7]); s3 = fmaf(t7, t7, s3);
            if ((k & 3) == 3) {
                float st = __builtin_amdgcn_exp2f(-((s0 + s1) + (s2 + s3)));
                SBUF[(k >> 2) * STR + tid] = st;
                s0 = s1 = s2 = s3 = 0.f;
            }
        }
    }

    __builtin_amdgcn_sched_barrier(0);  // keep ck loads out of phase A's budget

    // ---------------- phase B: consequent -> pv = st*ro -> PBUF ----------------
    {
        float ck_[DD], bias;
        #pragma unroll
        for (int d = 0; d < DD; ++d) ck_[d] = C[tid * (DD + 1) + d];
        bias = C[tid * (DD + 1) + DD];
        #pragma unroll
        for (int d = 0; d < DD; ++d) asm("" : "+v"(ck_[d]));
        asm("" : "+v"(bias));

        float4 q[4][2];
        #pragma unroll
        for (int k = 0; k < 3; ++k) {
            const float4* p = (const float4*)(xp + k * 8);
            q[k][0] = p[0]; q[k][1] = p[1];
        }
        float r0 = bias, r1 = 0.f, r2 = 0.f, r3 = 0.f;
        #pragma unroll
        for (int k = 0; k < NQ; ++k) {
            if (k + 3 < NQ) {
                const float4* p = (const float4*)(xp + (k + 3) * 8);
                q[(k + 3) & 3][0] = p[0]; q[(k + 3) & 3][1] = p[1];
            }
            const int d0 = (k & 3) * 8;
            float4 v0 = q[k & 3][0], v1 = q[k & 3][1];
            r0 = fmaf(v0.x, ck_[d0+0], r0);
            r1 = fmaf(v0.y, ck_[d0+1], r1);
            r2 = fmaf(v0.z, ck_[d0+2], r2);
            r3 = fmaf(v0.w, ck_[d0+3], r3);
            r0 = fmaf(v1.x, ck_[d0+4], r0);
            r1 = fmaf(v1.y, ck_[d0+5], r1);
            r2 = fmaf(v1.z, ck_[d0+6], r2);
            r3 = fmaf(v1.w, ck_[d0+7], r3);
            if ((k & 3) == 3) {
                const int j = k >> 2;
                float st = SBUF[j * STR + tid];   // same-thread RAW, no barrier
                PBUF[j * STR + tid] = st * ((r0 + r1) + (r2 + r3));
                r0 = bias; r1 = r2 = r3 = 0.f;
            }
        }
    }
    __syncthreads();

    // ---- per-sample sums over rules: 128 threads = 16 samples x 8 octants ----
    {
        int s = tid >> 3, o = tid & 7;      // 16B-group o covers 16 floats
        const float4* srow = (const float4*)&SBUF[s * STR + o * 16];
        const float4* prow = (const float4*)&PBUF[s * STR + o * 16];
        float ss = 0.f, dd = 0.f;
        #pragma unroll
        for (int k = 0; k < 4; ++k) {
            float4 v = srow[k]; ss += (v.x + v.y) + (v.z + v.w);
            float4 p = prow[k]; dd += (p.x + p.y) + (p.z + p.w);
        }
        pS[s][o] = ss; pD[s][o] = dd;
    }
    __syncthreads();
    if (tid < SPB) {
        float ss = 0.f, dd = 0.f;
        #pragma unroll
        for (int o = 0; o < 8; ++o) { ss += pS[tid][o]; dd += pD[tid][o]; }
        float sc = 1.0f / (ss + 1e-8f);
        out_pred[nbase + tid] = dd * sc;
        scale_lds[tid] = sc;
    }
    __syncthreads();

    // ---- flush strengths + normalized, float4-coalesced ----
    #pragma unroll
    for (int it = 0; it < 4; ++it) {
        int f   = it * 128 + tid;       // float4 index over 16x32 tile
        int row = f >> 5;
        int col = f & 31;
        float4 v = *(const float4*)&SBUF[row * STR + col * 4];
        float sc = scale_lds[row];
        size_t base = ((size_t)(nbase + row)) * RR + col * 4;
        *(float4*)(out_str  + base) = v;
        *(float4*)(out_norm + base) = make_float4(v.x * sc, v.y * sc, v.z * sc, v.w * sc);
    }
}

extern "C" void kernel_launch(void* const* d_in, const int* in_sizes, int n_in,
                              void* d_out, int out_size, void* d_ws, size_t ws_size,
                              hipStream_t stream) {
    const float* X = (const float*)d_in[0];
    const float* A = (const float*)d_in[1];
    const float* B = (const float*)d_in[2];
    const float* C = (const float*)d_in[3];

    float* pred = (float*)d_out;
    float* str  = pred + NS;
    float* nrm  = str + (size_t)NS * RR;

    anfis_main<<<dim3(NS / SPB), dim3(128), 0, stream>>>(X, A, B, C, pred, str, nrm);
}

// Round 2
// 114.143 us; speedup vs baseline: 1.4096x; 1.4096x over previous
//
#include <hip/hip_runtime.h>

#define NS 65536
#define DD 32
#define RR 128
#define SPB 16            // samples per block
#define STR 132           // padded LDS row stride (floats)

// R6: broadcast X through the VALU pipe (v_readlane), not SMEM and not per-lane VMEM.
// R4 (45.5us, VALU 33%): SMEM x-loads -> unordered returns -> lgkmcnt(0) drain per
// sample pair -> ~1000cy cold-HBM latency exposed 8x per block.
// R5 (103us): per-lane VMEM x + full 64-iter unroll -> VGPR collapsed to 56
// (AGPR/scratch juggling) + ~25KB loop bodies (I-cache thrash).
// R6: each WAVE holds the whole 2KB X tile in 8 VGPRs/lane (2 coalesced dwordx4,
// issued at block start together with the param loads => ONE vmcnt latency
// exposure per block, hidden by ~8 resident blocks/CU). x[s][d] is broadcast with
// v_readlane_b32 (lane = s*4 + d/8, SGPR-indexed; full-rate VALU, no waitcnt),
// and feeds the FMA as its single SGPR operand — identical accumulation order to
// R4 => bit-identical outputs. Loop kept rolled (unroll 2, ~1KB body).
__global__ __launch_bounds__(128, 4) void anfis_main(
    const float* __restrict__ X, const float* __restrict__ A,
    const float* __restrict__ B, const float* __restrict__ C,
    float* __restrict__ out_pred, float* __restrict__ out_str,
    float* __restrict__ out_norm)
{
    __shared__ float SBUF[SPB * STR];   // strengths, row = sample-in-block
    __shared__ float PBUF[SPB * STR];   // strength * rule_out
    __shared__ float pS[SPB][8];
    __shared__ float pD[SPB][8];
    __shared__ float scale_lds[SPB];

    const int tid   = threadIdx.x;      // rule id
    const int nbase = blockIdx.x * SPB;

    // ---- per-wave copy of the block's X tile: lane lw holds floats lw*8..lw*8+7
    // (sample lw/4, dims (lw%4)*8 .. +7). Both waves load the same 2KB (2nd hits L1).
    const int lw = tid & 63;
    const float4* xg = (const float4*)(X + (size_t)nbase * DD) + lw * 2;
    float4 vx0 = xg[0];                 // dims (lw%4)*8 + 0..3
    float4 vx1 = xg[1];                 // dims (lw%4)*8 + 4..7

    // ---- per-thread rule params -> VGPRs (loaded once, then pinned) ----
    float w_[DD], naw_[DD], ck_[DD], bias;
    {
        const float4* av = (const float4*)(A + tid * DD);
        const float4* bv = (const float4*)(B + tid * DD);
        #pragma unroll
        for (int i = 0; i < 8; ++i) {
            float4 va = av[i], vb = bv[i];
            float w0 = 0.8493218003f * __builtin_amdgcn_rcpf(fmaxf(vb.x, 1e-8f));
            float w1 = 0.8493218003f * __builtin_amdgcn_rcpf(fmaxf(vb.y, 1e-8f));
            float w2 = 0.8493218003f * __builtin_amdgcn_rcpf(fmaxf(vb.z, 1e-8f));
            float w3 = 0.8493218003f * __builtin_amdgcn_rcpf(fmaxf(vb.w, 1e-8f));
            w_[4*i+0] = w0; naw_[4*i+0] = -va.x * w0;
            w_[4*i+1] = w1; naw_[4*i+1] = -va.y * w1;
            w_[4*i+2] = w2; naw_[4*i+2] = -va.z * w2;
            w_[4*i+3] = w3; naw_[4*i+3] = -va.w * w3;
        }
        #pragma unroll
        for (int d = 0; d < DD; ++d) ck_[d] = C[tid * (DD + 1) + d];
        bias = C[tid * (DD + 1) + DD];
    }
    // Pin: forbid rematerialization/reload inside the sample loop.
    #pragma unroll
    for (int d = 0; d < DD; ++d)
        asm("" : "+v"(w_[d]), "+v"(naw_[d]), "+v"(ck_[d]));
    asm("" : "+v"(bias));
    asm("" : "+v"(vx0.x), "+v"(vx0.y), "+v"(vx0.z), "+v"(vx0.w));
    asm("" : "+v"(vx1.x), "+v"(vx1.y), "+v"(vx1.z), "+v"(vx1.w));

    // broadcast x[sample j][dim d] from lane (j*4 + d/8), element d%8
    #define XRD(vv, comp, lane) \
        __int_as_float(__builtin_amdgcn_readlane(__float_as_int((vv).comp), (lane)))

    #pragma unroll 2
    for (int j = 0; j < SPB; ++j) {
        const int lbase = j * 4;
        float s0 = 0.f, s1 = 0.f, s2 = 0.f, s3 = 0.f;
        float r0 = bias, r1 = 0.f, r2 = 0.f, r3 = 0.f;
        #pragma unroll
        for (int d = 0; d < DD; d += 4) {
            const int lane = lbase + (d >> 3);
            float x0, x1, x2, x3;
            if ((d & 4) == 0) {
                x0 = XRD(vx0, x, lane); x1 = XRD(vx0, y, lane);
                x2 = XRD(vx0, z, lane); x3 = XRD(vx0, w, lane);
            } else {
                x0 = XRD(vx1, x, lane); x1 = XRD(vx1, y, lane);
                x2 = XRD(vx1, z, lane); x3 = XRD(vx1, w, lane);
            }
            float t0 = fmaf(x0, w_[d+0], naw_[d+0]); s0 = fmaf(t0, t0, s0); r0 = fmaf(x0, ck_[d+0], r0);
            float t1 = fmaf(x1, w_[d+1], naw_[d+1]); s1 = fmaf(t1, t1, s1); r1 = fmaf(x1, ck_[d+1], r1);
            float t2 = fmaf(x2, w_[d+2], naw_[d+2]); s2 = fmaf(t2, t2, s2); r2 = fmaf(x2, ck_[d+2], r2);
            float t3 = fmaf(x3, w_[d+3], naw_[d+3]); s3 = fmaf(t3, t3, s3); r3 = fmaf(x3, ck_[d+3], r3);
        }
        float st = __builtin_amdgcn_exp2f(-((s0 + s1) + (s2 + s3)));
        float ro = (r0 + r1) + (r2 + r3);
        SBUF[j * STR + tid] = st;
        PBUF[j * STR + tid] = st * ro;
    }
    #undef XRD
    __syncthreads();

    // ---- per-sample sums over rules: 128 threads = 16 samples x 8 octants ----
    {
        int s = tid >> 3, o = tid & 7;      // 16B-group o covers 16 floats
        const float4* srow = (const float4*)&SBUF[s * STR + o * 16];
        const float4* prow = (const float4*)&PBUF[s * STR + o * 16];
        float ss = 0.f, dd = 0.f;
        #pragma unroll
        for (int k = 0; k < 4; ++k) {
            float4 v = srow[k]; ss += (v.x + v.y) + (v.z + v.w);
            float4 p = prow[k]; dd += (p.x + p.y) + (p.z + p.w);
        }
        pS[s][o] = ss; pD[s][o] = dd;
    }
    __syncthreads();
    if (tid < SPB) {
        float ss = 0.f, dd = 0.f;
        #pragma unroll
        for (int o = 0; o < 8; ++o) { ss += pS[tid][o]; dd += pD[tid][o]; }
        float sc = 1.0f / (ss + 1e-8f);
        out_pred[nbase + tid] = dd * sc;
        scale_lds[tid] = sc;
    }
    __syncthreads();

    // ---- flush strengths + normalized, float4-coalesced ----
    #pragma unroll
    for (int it = 0; it < 4; ++it) {
        int f   = it * 128 + tid;       // float4 index over 16x32 tile
        int row = f >> 5;
        int col = f & 31;
        float4 v = *(const float4*)&SBUF[row * STR + col * 4];
        float sc = scale_lds[row];
        size_t base = ((size_t)(nbase + row)) * RR + col * 4;
        *(float4*)(out_str  + base) = v;
        *(float4*)(out_norm + base) = make_float4(v.x * sc, v.y * sc, v.z * sc, v.w * sc);
    }
}

extern "C" void kernel_launch(void* const* d_in, const int* in_sizes, int n_in,
                              void* d_out, int out_size, void* d_ws, size_t ws_size,
                              hipStream_t stream) {
    const float* X = (const float*)d_in[0];
    const float* A = (const float*)d_in[1];
    const float* B = (const float*)d_in[2];
    const float* C = (const float*)d_in[3];

    float* pred = (float*)d_out;
    float* str  = pred + NS;
    float* nrm  = str + (size_t)NS * RR;

    anfis_main<<<dim3(NS / SPB), dim3(128), 0, stream>>>(X, A, B, C, pred, str, nrm);
}

// Round 3
// 107.895 us; speedup vs baseline: 1.4912x; 1.0579x over previous
//
#include <hip/hip_runtime.h>

#define NS 65536
#define DD 32
#define RR 128
#define SPB 16            // samples per block
#define STR 132           // padded LDS row stride (floats)

// R7: X broadcast via wave-uniform ds_read_b128 (LDS pipe) + VGPR-budget fix.
// R4 (45.5us): SMEM x -> lgkmcnt(0) drains (latency-bound, VALU 33%).
// R6 (47.8us): readlane broadcast fixed latency (VALU 59%) but VGPR_Count=64
//   => the 97 pinned params live in AGPRs at the (128,4) 128-reg budget; each
//   use pays v_accvgpr_read, ~doubling the VALU stream (28us issue vs 14us useful).
// R7 fixes both terms:
//   (a) __launch_bounds__(128,3): ~168-reg budget vs ~145 demand -> params stay
//       in arch VGPRs, no accvgpr traffic. 3 waves/SIMD is plenty: we are
//       issue-bound, not latency-bound.
//   (b) X tile staged to LDS once/block; inner loop reads 4 dims with ONE
//       wave-uniform ds_read_b128 (same-address broadcast, conflict-free, LDS
//       pipe) instead of 4 readlanes (VALU pipe). 512 VALU ops/wave removed.
//   Half-sample double-buffer (2x 4xfloat4 = 32 regs) gives ~96cy of FMA
//   between a ds_read and its use.
// Arithmetic is op-for-op identical to R4/R6 => bit-identical outputs.
__global__ __launch_bounds__(128, 3) void anfis_main(
    const float* __restrict__ X, const float* __restrict__ A,
    const float* __restrict__ B, const float* __restrict__ C,
    float* __restrict__ out_pred, float* __restrict__ out_str,
    float* __restrict__ out_norm)
{
    __shared__ float SBUF[SPB * STR];   // strengths, row = sample-in-block
    __shared__ float PBUF[SPB * STR];   // strength * rule_out
    __shared__ float XT[SPB * DD];      // block's X tile (512 floats)
    __shared__ float pS[SPB][8];
    __shared__ float pD[SPB][8];
    __shared__ float scale_lds[SPB];

    const int tid   = threadIdx.x;      // rule id
    const int nbase = blockIdx.x * SPB;

    // ---- stage X tile to LDS (coalesced 2KB, 1 float4/thread) ----
    ((float4*)XT)[tid] = ((const float4*)(X + (size_t)nbase * DD))[tid];

    // ---- per-thread rule params -> VGPRs (overlap with X staging) ----
    float w_[DD], naw_[DD], ck_[DD], bias;
    {
        const float4* av = (const float4*)(A + tid * DD);
        const float4* bv = (const float4*)(B + tid * DD);
        #pragma unroll
        for (int i = 0; i < 8; ++i) {
            float4 va = av[i], vb = bv[i];
            float w0 = 0.8493218003f * __builtin_amdgcn_rcpf(fmaxf(vb.x, 1e-8f));
            float w1 = 0.8493218003f * __builtin_amdgcn_rcpf(fmaxf(vb.y, 1e-8f));
            float w2 = 0.8493218003f * __builtin_amdgcn_rcpf(fmaxf(vb.z, 1e-8f));
            float w3 = 0.8493218003f * __builtin_amdgcn_rcpf(fmaxf(vb.w, 1e-8f));
            w_[4*i+0] = w0; naw_[4*i+0] = -va.x * w0;
            w_[4*i+1] = w1; naw_[4*i+1] = -va.y * w1;
            w_[4*i+2] = w2; naw_[4*i+2] = -va.z * w2;
            w_[4*i+3] = w3; naw_[4*i+3] = -va.w * w3;
        }
        #pragma unroll
        for (int d = 0; d < DD; ++d) ck_[d] = C[tid * (DD + 1) + d];
        bias = C[tid * (DD + 1) + DD];
    }
    __syncthreads();                    // XT visible to both waves

    // Pin: forbid rematerialization/reload of params inside the sample loop.
    #pragma unroll
    for (int d = 0; d < DD; ++d)
        asm("" : "+v"(w_[d]), "+v"(naw_[d]), "+v"(ck_[d]));
    asm("" : "+v"(bias));

    // load half-sample (16 dims) of sample jj, half hh, into 4 float4s:
    // 4 wave-uniform ds_read_b128 -> LDS pipe broadcast, no bank conflicts.
    #define LOADH(buf, jj, hh) { _Pragma("unroll") \
        for (int g = 0; g < 4; ++g) \
            buf[g] = *(const float4*)&XT[(jj) * DD + (hh) * 16 + g * 4]; }

    // process 16 dims starting at d0 (same op order as R4 -> bit-identical)
    #define COMPUTEH(buf, d0) { _Pragma("unroll") \
        for (int g = 0; g < 4; ++g) { \
            const int d = (d0) + g * 4; \
            float4 v = buf[g]; \
            float t0 = fmaf(v.x, w_[d+0], naw_[d+0]); s0 = fmaf(t0, t0, s0); r0 = fmaf(v.x, ck_[d+0], r0); \
            float t1 = fmaf(v.y, w_[d+1], naw_[d+1]); s1 = fmaf(t1, t1, s1); r1 = fmaf(v.y, ck_[d+1], r1); \
            float t2 = fmaf(v.z, w_[d+2], naw_[d+2]); s2 = fmaf(t2, t2, s2); r2 = fmaf(v.z, ck_[d+2], r2); \
            float t3 = fmaf(v.w, w_[d+3], naw_[d+3]); s3 = fmaf(t3, t3, s3); r3 = fmaf(v.w, ck_[d+3], r3); \
        } }

    float4 qa[4], qb[4];
    LOADH(qa, 0, 0)
    #pragma unroll 2
    for (int j = 0; j < SPB; ++j) {
        float s0 = 0.f, s1 = 0.f, s2 = 0.f, s3 = 0.f;
        float r0 = bias, r1 = 0.f, r2 = 0.f, r3 = 0.f;
        LOADH(qb, j, 1)                     // issue reads for 2nd half of j
        COMPUTEH(qa, 0)                     // ~96cy of FMA covers the latency
        LOADH(qa, (j + 1) & (SPB - 1), 0)   // issue reads for 1st half of j+1
        COMPUTEH(qb, 16)
        float st = __builtin_amdgcn_exp2f(-((s0 + s1) + (s2 + s3)));
        float ro = (r0 + r1) + (r2 + r3);
        SBUF[j * STR + tid] = st;
        PBUF[j * STR + tid] = st * ro;
    }
    #undef LOADH
    #undef COMPUTEH
    __syncthreads();

    // ---- per-sample sums over rules: 128 threads = 16 samples x 8 octants ----
    {
        int s = tid >> 3, o = tid & 7;      // 16B-group o covers 16 floats
        const float4* srow = (const float4*)&SBUF[s * STR + o * 16];
        const float4* prow = (const float4*)&PBUF[s * STR + o * 16];
        float ss = 0.f, dd = 0.f;
        #pragma unroll
        for (int k = 0; k < 4; ++k) {
            float4 v = srow[k]; ss += (v.x + v.y) + (v.z + v.w);
            float4 p = prow[k]; dd += (p.x + p.y) + (p.z + p.w);
        }
        pS[s][o] = ss; pD[s][o] = dd;
    }
    __syncthreads();
    if (tid < SPB) {
        float ss = 0.f, dd = 0.f;
        #pragma unroll
        for (int o = 0; o < 8; ++o) { ss += pS[tid][o]; dd += pD[tid][o]; }
        float sc = 1.0f / (ss + 1e-8f);
        out_pred[nbase + tid] = dd * sc;
        scale_lds[tid] = sc;
    }
    __syncthreads();

    // ---- flush strengths + normalized, float4-coalesced ----
    #pragma unroll
    for (int it = 0; it < 4; ++it) {
        int f   = it * 128 + tid;       // float4 index over 16x32 tile
        int row = f >> 5;
        int col = f & 31;
        float4 v = *(const float4*)&SBUF[row * STR + col * 4];
        float sc = scale_lds[row];
        size_t base = ((size_t)(nbase + row)) * RR + col * 4;
        *(float4*)(out_str  + base) = v;
        *(float4*)(out_norm + base) = make_float4(v.x * sc, v.y * sc, v.z * sc, v.w * sc);
    }
}

extern "C" void kernel_launch(void* const* d_in, const int* in_sizes, int n_in,
                              void* d_out, int out_size, void* d_ws, size_t ws_size,
                              hipStream_t stream) {
    const float* X = (const float*)d_in[0];
    const float* A = (const float*)d_in[1];
    const float* B = (const float*)d_in[2];
    const float* C = (const float*)d_in[3];

    float* pred = (float*)d_out;
    float* str  = pred + NS;
    float* nrm  = str + (size_t)NS * RR;

    anfis_main<<<dim3(NS / SPB), dim3(128), 0, stream>>>(X, A, B, C, pred, str, nrm);
}